// Round 5
// baseline (798.475 us; speedup 1.0000x reference)
//
#include <hip/hip_runtime.h>

#define NN 40000
#define DDIM 64
#define KE 16
#define EE 640000
#define BNEPS 1e-5f

// Finalize BN coefficients from raw sums: stats layout [sum[C], sumsq[C]].
__device__ __forceinline__ void bn_coeff(const float* __restrict__ S, int C, int c,
                                         const float* __restrict__ g, const float* __restrict__ b,
                                         float inv_n, float& sc, float& sh)
{
    float m   = S[c] * inv_n;
    float var = S[C + c] * inv_n - m * m;
    float r   = rsqrtf(var + BNEPS);
    sc = g[c] * r;
    sh = b[c] - m * sc;
}

// out[r][c] = sum_d f(in[r][d]) * W[d][c], 64x64 W, optional BN+ReLU input transform,
// optional raw column-stats accumulation on the output.
template<int TRN>
__global__ __launch_bounds__(256) void gemm64_k(
    const float* __restrict__ in,
    const float* __restrict__ W0, const float* __restrict__ W1, const float* __restrict__ W2,
    float* __restrict__ out0, float* __restrict__ out1, float* __restrict__ out2,
    const float* __restrict__ Sin, const float* __restrict__ gamma, const float* __restrict__ beta,
    float inv_n, float* __restrict__ Sout)
{
    const float* W = (blockIdx.y == 0) ? W0 : ((blockIdx.y == 1) ? W1 : W2);
    float* out     = (blockIdx.y == 0) ? out0 : ((blockIdx.y == 1) ? out1 : out2);

    __shared__ float Wl[64][64];
    __shared__ float inl[64][65];
    __shared__ float scl[64], shl[64];
    __shared__ float ssum[64], ssq[64];

    const int t = threadIdx.x;
    if (t < 64) {
        if (TRN) { float sc, sh; bn_coeff(Sin, 64, t, gamma, beta, inv_n, sc, sh); scl[t] = sc; shl[t] = sh; }
        ssum[t] = 0.f; ssq[t] = 0.f;
    }
#pragma unroll
    for (int i = 0; i < 16; i++) { int idx = t + i * 256; Wl[idx >> 6][idx & 63] = W[idx]; }
    __syncthreads();

    const int rbase = blockIdx.x * 64;
    {
        const int d = t & 63;
        float sc = 0.f, sh = 0.f;
        if (TRN) { sc = scl[d]; sh = shl[d]; }
#pragma unroll
        for (int i = 0; i < 16; i++) {
            int r = (t >> 6) + i * 4;
            float v = in[(size_t)(rbase + r) * 64 + d];
            if (TRN) v = fmaxf(fmaf(v, sc, sh), 0.f);
            inl[r][d] = v;
        }
    }
    __syncthreads();

    const int c0 = (t & 15) * 4, r0 = (t >> 4) * 4;
    float acc[4][4] = {};
#pragma unroll 16
    for (int d = 0; d < 64; d++) {
        float4 w4 = *(const float4*)&Wl[d][c0];
#pragma unroll
        for (int i = 0; i < 4; i++) {
            float h = inl[r0 + i][d];
            acc[i][0] = fmaf(h, w4.x, acc[i][0]);
            acc[i][1] = fmaf(h, w4.y, acc[i][1]);
            acc[i][2] = fmaf(h, w4.z, acc[i][2]);
            acc[i][3] = fmaf(h, w4.w, acc[i][3]);
        }
    }
#pragma unroll
    for (int i = 0; i < 4; i++) {
        float4 o; o.x = acc[i][0]; o.y = acc[i][1]; o.z = acc[i][2]; o.w = acc[i][3];
        *(float4*)&out[(size_t)(rbase + r0 + i) * 64 + c0] = o;
    }
    if (Sout) {
#pragma unroll
        for (int j = 0; j < 4; j++) {
            float s  = acc[0][j] + acc[1][j] + acc[2][j] + acc[3][j];
            float qv = acc[0][j] * acc[0][j] + acc[1][j] * acc[1][j] + acc[2][j] * acc[2][j] + acc[3][j] * acc[3][j];
            atomicAdd(&ssum[c0 + j], s);
            atomicAdd(&ssq[c0 + j], qv);
        }
        __syncthreads();
        if (t < 64) { atomicAdd(&Sout[t], ssum[t]); atomicAdd(&Sout[64 + t], ssq[t]); }
    }
}

// q = (pos[dst]-pos[src]) @ Wp1 + bp1, stored SoA; accumulate raw stats (3 cols).
__global__ __launch_bounds__(256) void edge_q_k(
    const float* __restrict__ pos, const int* __restrict__ src,
    const float* __restrict__ Wp1, const float* __restrict__ bp1,
    float* __restrict__ q0, float* __restrict__ q1, float* __restrict__ q2,
    float* __restrict__ Sq)
{
    float w00 = Wp1[0], w01 = Wp1[1], w02 = Wp1[2];
    float w10 = Wp1[3], w11 = Wp1[4], w12 = Wp1[5];
    float w20 = Wp1[6], w21 = Wp1[7], w22 = Wp1[8];
    float c0 = bp1[0], c1 = bp1[1], c2 = bp1[2];
    float s0 = 0, s1 = 0, s2 = 0, p0 = 0, p1 = 0, p2 = 0;
    for (int e = blockIdx.x * blockDim.x + threadIdx.x; e < EE; e += gridDim.x * blockDim.x) {
        int sj = src[e]; int di = e >> 4;
        float r0 = pos[di * 3 + 0] - pos[sj * 3 + 0];
        float r1 = pos[di * 3 + 1] - pos[sj * 3 + 1];
        float r2 = pos[di * 3 + 2] - pos[sj * 3 + 2];
        float v0 = c0 + r0 * w00 + r1 * w10 + r2 * w20;
        float v1 = c1 + r0 * w01 + r1 * w11 + r2 * w21;
        float v2 = c2 + r0 * w02 + r1 * w12 + r2 * w22;
        q0[e] = v0; q1[e] = v1; q2[e] = v2;
        s0 += v0; s1 += v1; s2 += v2;
        p0 += v0 * v0; p1 += v1 * v1; p2 += v2 * v2;
    }
#pragma unroll
    for (int o = 32; o > 0; o >>= 1) {
        s0 += __shfl_down(s0, o); s1 += __shfl_down(s1, o); s2 += __shfl_down(s2, o);
        p0 += __shfl_down(p0, o); p1 += __shfl_down(p1, o); p2 += __shfl_down(p2, o);
    }
    if ((threadIdx.x & 63) == 0) {
        atomicAdd(&Sq[0], s0); atomicAdd(&Sq[1], s1); atomicAdd(&Sq[2], s2);
        atomicAdd(&Sq[3], p0); atomicAdd(&Sq[4], p1); atomicAdd(&Sq[5], p2);
    }
}

// Store-free raw column stats of a0 = a_dst[dst] - a_src[src] + delta  (64 cols over E rows).
__global__ __launch_bounds__(256) void edge_a0_k(
    const float* __restrict__ q0, const float* __restrict__ q1, const float* __restrict__ q2,
    const int* __restrict__ src,
    const float* __restrict__ adst, const float* __restrict__ asrc,
    const float* __restrict__ Wp2, const float* __restrict__ bp2,
    const float* __restrict__ Sq, const float* __restrict__ gp, const float* __restrict__ bp_,
    float* __restrict__ Sa0)
{
    const int lane = threadIdx.x & 63;
    const int wid  = (blockIdx.x * blockDim.x + threadIdx.x) >> 6;
    const int nw   = (gridDim.x * blockDim.x) >> 6;
    const float inv_e = 1.0f / (float)EE;
    float sc30, sh30, sc31, sh31, sc32, sh32;
    bn_coeff(Sq, 3, 0, gp, bp_, inv_e, sc30, sh30);
    bn_coeff(Sq, 3, 1, gp, bp_, inv_e, sc31, sh31);
    bn_coeff(Sq, 3, 2, gp, bp_, inv_e, sc32, sh32);
    float w0 = Wp2[lane], w1 = Wp2[64 + lane], w2 = Wp2[128 + lane], bd = bp2[lane];
    float s = 0.f, sq = 0.f;
    for (int e = wid; e < EE; e += nw) {
        float ph0 = fmaxf(fmaf(q0[e], sc30, sh30), 0.f);
        float ph1 = fmaxf(fmaf(q1[e], sc31, sh31), 0.f);
        float ph2 = fmaxf(fmaf(q2[e], sc32, sh32), 0.f);
        float dl  = bd + ph0 * w0 + ph1 * w1 + ph2 * w2;
        float a0  = adst[(size_t)(e >> 4) * 64 + lane] - asrc[(size_t)src[e] * 64 + lane] + dl;
        s += a0; sq += a0 * a0;
    }
    __shared__ float ls[64], lq[64];
    if (threadIdx.x < 64) { ls[threadIdx.x] = 0.f; lq[threadIdx.x] = 0.f; }
    __syncthreads();
    atomicAdd(&ls[lane], s); atomicAdd(&lq[lane], sq);
    __syncthreads();
    if (threadIdx.x < 64) { atomicAdd(&Sa0[threadIdx.x], ls[threadIdx.x]); atomicAdd(&Sa0[64 + threadIdx.x], lq[threadIdx.x]); }
}

// t = relu(bn(a0)) @ Wa1 + ba1  [E,8]; a1 recomputed into LDS; raw stats (8 cols).
__global__ __launch_bounds__(128) void edge_t_k(
    const float* __restrict__ q0, const float* __restrict__ q1, const float* __restrict__ q2,
    const int* __restrict__ src,
    const float* __restrict__ adst, const float* __restrict__ asrc,
    const float* __restrict__ Wp2, const float* __restrict__ bp2,
    const float* __restrict__ Sq, const float* __restrict__ gp, const float* __restrict__ bp_,
    const float* __restrict__ Sa0, const float* __restrict__ ga0, const float* __restrict__ ba0,
    const float* __restrict__ Wa1, const float* __restrict__ ba1,
    float* __restrict__ tout, float* __restrict__ St)
{
    __shared__ float a1l[128][65];
    __shared__ float wl[64][8];
    __shared__ float red[16];
    const int t = threadIdx.x;
    const int lane = t & 63;
    const float inv_e = 1.0f / (float)EE;
    float sc30, sh30, sc31, sh31, sc32, sh32;
    bn_coeff(Sq, 3, 0, gp, bp_, inv_e, sc30, sh30);
    bn_coeff(Sq, 3, 1, gp, bp_, inv_e, sc31, sh31);
    bn_coeff(Sq, 3, 2, gp, bp_, inv_e, sc32, sh32);
    float scA, shA; bn_coeff(Sa0, 64, lane, ga0, ba0, inv_e, scA, shA);
    float w0 = Wp2[lane], w1 = Wp2[64 + lane], w2 = Wp2[128 + lane], bd = bp2[lane];
    for (int i = t; i < 512; i += 128) wl[i >> 3][i & 7] = Wa1[i];
    if (t < 16) red[t] = 0.f;
    float b8[8];
#pragma unroll
    for (int k = 0; k < 8; k++) b8[k] = ba1[k];
    float ss[8] = {}, sp[8] = {};

    for (int it = 0; it < 4; ++it) {
        __syncthreads();
        const int e0 = (blockIdx.x + it * 1250) * 128;
        // stage a1 tile: thread covers fixed d=lane, edges (t>>6)+i*2
        for (int i = 0; i < 64; i++) {
            int el = (t >> 6) + i * 2;
            int e  = e0 + el;
            float ph0 = fmaxf(fmaf(q0[e], sc30, sh30), 0.f);
            float ph1 = fmaxf(fmaf(q1[e], sc31, sh31), 0.f);
            float ph2 = fmaxf(fmaf(q2[e], sc32, sh32), 0.f);
            float dl  = bd + ph0 * w0 + ph1 * w1 + ph2 * w2;
            float a0  = adst[(size_t)(e >> 4) * 64 + lane] - asrc[(size_t)src[e] * 64 + lane] + dl;
            a1l[el][lane] = fmaxf(fmaf(a0, scA, shA), 0.f);
        }
        __syncthreads();
        {
            int e = e0 + t;
            float acc[8];
#pragma unroll
            for (int k = 0; k < 8; k++) acc[k] = b8[k];
#pragma unroll 8
            for (int dd = 0; dd < 64; dd++) {
                float a = a1l[t][dd];
                float4 lo = *(const float4*)&wl[dd][0];
                float4 hi = *(const float4*)&wl[dd][4];
                acc[0] = fmaf(a, lo.x, acc[0]); acc[1] = fmaf(a, lo.y, acc[1]);
                acc[2] = fmaf(a, lo.z, acc[2]); acc[3] = fmaf(a, lo.w, acc[3]);
                acc[4] = fmaf(a, hi.x, acc[4]); acc[5] = fmaf(a, hi.y, acc[5]);
                acc[6] = fmaf(a, hi.z, acc[6]); acc[7] = fmaf(a, hi.w, acc[7]);
            }
            float4 o0, o1;
            o0.x = acc[0]; o0.y = acc[1]; o0.z = acc[2]; o0.w = acc[3];
            o1.x = acc[4]; o1.y = acc[5]; o1.z = acc[6]; o1.w = acc[7];
            *(float4*)&tout[(size_t)e * 8]     = o0;
            *(float4*)&tout[(size_t)e * 8 + 4] = o1;
#pragma unroll
            for (int k = 0; k < 8; k++) { ss[k] += acc[k]; sp[k] += acc[k] * acc[k]; }
        }
    }
#pragma unroll
    for (int o = 32; o > 0; o >>= 1) {
#pragma unroll
        for (int k = 0; k < 8; k++) { ss[k] += __shfl_down(ss[k], o); sp[k] += __shfl_down(sp[k], o); }
    }
    if (lane == 0) {
#pragma unroll
        for (int k = 0; k < 8; k++) { atomicAdd(&red[k], ss[k]); atomicAdd(&red[8 + k], sp[k]); }
    }
    __syncthreads();
    if (t < 16) atomicAdd(&St[t], red[t]);
}

// Per-node (wave) fused: a2=relu(bn(t)); a3=a2@Wa2+ba2; softmax over 16 edges; agg; raw stats.
__global__ __launch_bounds__(256) void edge_final_k(
    const float* __restrict__ tin,
    const float* __restrict__ q0, const float* __restrict__ q1, const float* __restrict__ q2,
    const int* __restrict__ src, const float* __restrict__ vv,
    const float* __restrict__ Wp2, const float* __restrict__ bp2,
    const float* __restrict__ Sq, const float* __restrict__ gp, const float* __restrict__ bp_,
    const float* __restrict__ St, const float* __restrict__ ga1, const float* __restrict__ bb1,
    const float* __restrict__ Wa2, const float* __restrict__ ba2,
    float* __restrict__ agg, float* __restrict__ Sagg)
{
    const int t = threadIdx.x, lane = t & 63, w = t >> 6;
    const float inv_e = 1.0f / (float)EE;
    float sc3[3], sh3[3];
#pragma unroll
    for (int k = 0; k < 3; k++) bn_coeff(Sq, 3, k, gp, bp_, inv_e, sc3[k], sh3[k]);
    float sc8[8], sh8[8];
#pragma unroll
    for (int k = 0; k < 8; k++) bn_coeff(St, 8, k, ga1, bb1, inv_e, sc8[k], sh8[k]);
    float wa[8];
#pragma unroll
    for (int k = 0; k < 8; k++) wa[k] = Wa2[k * 64 + lane];
    float bad = ba2[lane];
    float wp0 = Wp2[lane], wp1 = Wp2[64 + lane], wp2 = Wp2[128 + lane];
    float bpd = bp2[lane];
    float ssum = 0.f, ssq = 0.f;

    for (int nn = 0; nn < 4; nn++) {
        int i = blockIdx.x * 16 + nn * 4 + w;
        float ax[16], dl[16], vs[16];
        float m = -3.0e38f;
#pragma unroll
        for (int j = 0; j < 16; j++) {
            int e = i * 16 + j;
            const float4* tp = (const float4*)(tin + (size_t)e * 8);
            float4 ta = tp[0], tb = tp[1];
            float a20 = fmaxf(fmaf(ta.x, sc8[0], sh8[0]), 0.f);
            float a21 = fmaxf(fmaf(ta.y, sc8[1], sh8[1]), 0.f);
            float a22 = fmaxf(fmaf(ta.z, sc8[2], sh8[2]), 0.f);
            float a23 = fmaxf(fmaf(ta.w, sc8[3], sh8[3]), 0.f);
            float a24 = fmaxf(fmaf(tb.x, sc8[4], sh8[4]), 0.f);
            float a25 = fmaxf(fmaf(tb.y, sc8[5], sh8[5]), 0.f);
            float a26 = fmaxf(fmaf(tb.z, sc8[6], sh8[6]), 0.f);
            float a27 = fmaxf(fmaf(tb.w, sc8[7], sh8[7]), 0.f);
            float a = bad;
            a = fmaf(a20, wa[0], a); a = fmaf(a21, wa[1], a);
            a = fmaf(a22, wa[2], a); a = fmaf(a23, wa[3], a);
            a = fmaf(a24, wa[4], a); a = fmaf(a25, wa[5], a);
            a = fmaf(a26, wa[6], a); a = fmaf(a27, wa[7], a);
            float ph0 = fmaxf(fmaf(q0[e], sc3[0], sh3[0]), 0.f);
            float ph1 = fmaxf(fmaf(q1[e], sc3[1], sh3[1]), 0.f);
            float ph2 = fmaxf(fmaf(q2[e], sc3[2], sh3[2]), 0.f);
            dl[j] = bpd + ph0 * wp0 + ph1 * wp1 + ph2 * wp2;
            vs[j] = vv[(size_t)src[e] * 64 + lane];
            ax[j] = a; m = fmaxf(m, a);
        }
        float s = 0.f;
#pragma unroll
        for (int j = 0; j < 16; j++) { ax[j] = __expf(ax[j] - m); s += ax[j]; }
        float inv = 1.0f / (s + 1e-16f);
        float ag = 0.f;
#pragma unroll
        for (int j = 0; j < 16; j++) ag += ax[j] * (vs[j] + dl[j]);
        ag *= inv;
        agg[(size_t)i * 64 + lane] = ag;
        ssum += ag; ssq += ag * ag;
    }
    __shared__ float ls[64], lq[64];
    if (t < 64) { ls[t] = 0.f; lq[t] = 0.f; }
    __syncthreads();
    atomicAdd(&ls[lane], ssum); atomicAdd(&lq[lane], ssq);
    __syncthreads();
    if (t < 64) { atomicAdd(&Sagg[t], ls[t]); atomicAdd(&Sagg[64 + t], lq[t]); }
}

// out = relu(bn(t2,g3,b3) + x)
__global__ __launch_bounds__(256) void final_k(
    const float* __restrict__ t2, const float* __restrict__ x,
    const float* __restrict__ St2, const float* __restrict__ g3, const float* __restrict__ b3,
    float* __restrict__ out)
{
    __shared__ float scl[64], shl[64];
    const int t = threadIdx.x;
    if (t < 64) { float sc, sh; bn_coeff(St2, 64, t, g3, b3, 1.0f / (float)NN, sc, sh); scl[t] = sc; shl[t] = sh; }
    __syncthreads();
    int idx = blockIdx.x * 256 + t;          // float4 index; NN*64/4 = 640000 exactly
    int c0 = (idx & 15) * 4;
    const float4 a = *(const float4*)&t2[(size_t)idx * 4];
    const float4 b = *(const float4*)&x[(size_t)idx * 4];
    float4 o;
    o.x = fmaxf(fmaf(a.x, scl[c0 + 0], shl[c0 + 0]) + b.x, 0.f);
    o.y = fmaxf(fmaf(a.y, scl[c0 + 1], shl[c0 + 1]) + b.y, 0.f);
    o.z = fmaxf(fmaf(a.z, scl[c0 + 2], shl[c0 + 2]) + b.z, 0.f);
    o.w = fmaxf(fmaf(a.w, scl[c0 + 3], shl[c0 + 3]) + b.w, 0.f);
    *(float4*)&out[(size_t)idx * 4] = o;
}

extern "C" void kernel_launch(void* const* d_in, const int* in_sizes, int n_in,
                              void* d_out, int out_size, void* d_ws, size_t ws_size,
                              hipStream_t stream)
{
    const float* x    = (const float*)d_in[0];
    const float* pos  = (const float*)d_in[1];
    const int*   src  = (const int*)d_in[2];      // edge_index[0]; dst[e] == e>>4 by construction
    const float* W_in = (const float*)d_in[3];
    const float* g1   = (const float*)d_in[4];
    const float* b1   = (const float*)d_in[5];
    const float* W_v  = (const float*)d_in[6];
    const float* W_src= (const float*)d_in[7];
    const float* W_dst= (const float*)d_in[8];
    const float* Wp1  = (const float*)d_in[9];
    const float* bp1  = (const float*)d_in[10];
    const float* gp   = (const float*)d_in[11];
    const float* bp_  = (const float*)d_in[12];
    const float* Wp2  = (const float*)d_in[13];
    const float* bp2  = (const float*)d_in[14];
    const float* ga0  = (const float*)d_in[15];
    const float* ba0  = (const float*)d_in[16];
    const float* Wa1  = (const float*)d_in[17];
    const float* ba1  = (const float*)d_in[18];
    const float* ga1  = (const float*)d_in[19];
    const float* bb1  = (const float*)d_in[20];
    const float* Wa2  = (const float*)d_in[21];
    const float* ba2  = (const float*)d_in[22];
    const float* g2   = (const float*)d_in[23];
    const float* b2   = (const float*)d_in[24];
    const float* W_out= (const float*)d_in[25];
    const float* g3   = (const float*)d_in[26];
    const float* b3   = (const float*)d_in[27];
    float* out = (float*)d_out;

    float* wsf   = (float*)d_ws;
    float* S_t1  = wsf;          // 128
    float* S_q   = wsf + 128;    // 6 used
    float* S_a0  = wsf + 192;    // 128
    float* S_t   = wsf + 320;    // 16 used
    float* S_agg = wsf + 384;    // 128
    float* S_t2  = wsf + 512;    // 128
    const size_t N64 = (size_t)NN * 64;
    float* t1   = wsf + 1024;
    float* asrc = t1 + N64;
    float* adst = asrc + N64;
    float* vv   = adst + N64;
    float* q0   = vv + N64;
    float* q1   = q0 + EE;
    float* q2   = q1 + EE;
    float* tt   = q2 + EE;       // [E,8]
    float* agg  = t1;            // alias: t1 dead after gemm #2
    float* t2   = asrc;          // alias: asrc dead after edge_t

    hipMemsetAsync(wsf, 0, 1024 * sizeof(float), stream);

    // t1 = x @ W_in (+stats)
    gemm64_k<0><<<dim3(625, 1), 256, 0, stream>>>(x, W_in, W_in, W_in, t1, t1, t1,
                                                  nullptr, nullptr, nullptr, 0.f, S_t1);
    // h = relu(bn(t1)); {asrc,adst,vv} = h @ {W_src,W_dst,W_v}
    gemm64_k<1><<<dim3(625, 3), 256, 0, stream>>>(t1, W_src, W_dst, W_v, asrc, adst, vv,
                                                  S_t1, g1, b1, 1.0f / (float)NN, nullptr);
    // q = (pos[dst]-pos[src]) @ Wp1 + bp1 (+stats3)
    edge_q_k<<<1024, 256, 0, stream>>>(pos, src, Wp1, bp1, q0, q1, q2, S_q);
    // raw stats of a0 (store-free)
    edge_a0_k<<<1024, 256, 0, stream>>>(q0, q1, q2, src, adst, asrc, Wp2, bp2, S_q, gp, bp_, S_a0);
    // t = relu(bn(a0)) @ Wa1 + ba1 (+stats8)
    edge_t_k<<<1250, 128, 0, stream>>>(q0, q1, q2, src, adst, asrc, Wp2, bp2, S_q, gp, bp_,
                                       S_a0, ga0, ba0, Wa1, ba1, tt, S_t);
    // a2,a3,softmax,agg (+stats)
    edge_final_k<<<2500, 256, 0, stream>>>(tt, q0, q1, q2, src, vv, Wp2, bp2, S_q, gp, bp_,
                                           S_t, ga1, bb1, Wa2, ba2, agg, S_agg);
    // t2 = relu(bn(agg,g2,b2)) @ W_out (+stats)
    gemm64_k<1><<<dim3(625, 1), 256, 0, stream>>>(agg, W_out, W_out, W_out, t2, t2, t2,
                                                  S_agg, g2, b2, 1.0f / (float)NN, S_t2);
    // out = relu(bn(t2,g3,b3) + x)
    final_k<<<2500, 256, 0, stream>>>(t2, x, S_t2, g3, b3, out);
}

// Round 6
// 696.987 us; speedup vs baseline: 1.1456x; 1.1456x over previous
//
#include <hip/hip_runtime.h>

#define NN 40000
#define DDIM 64
#define KE 16
#define EE 640000
#define BNEPS 1e-5f

// Finalize BN coefficients from raw sums: stats layout [sum[C], sumsq[C]].
__device__ __forceinline__ void bn_coeff(const float* __restrict__ S, int C, int c,
                                         const float* __restrict__ g, const float* __restrict__ b,
                                         float inv_n, float& sc, float& sh)
{
    float m   = S[c] * inv_n;
    float var = S[C + c] * inv_n - m * m;
    float r   = rsqrtf(var + BNEPS);
    sc = g[c] * r;
    sh = b[c] - m * sc;
}

// out[r][c] = sum_d f(in[r][d]) * W[d][c], 64x64 W, optional BN+ReLU input transform,
// optional raw column-stats accumulation on the output.
template<int TRN>
__global__ __launch_bounds__(256) void gemm64_k(
    const float* __restrict__ in,
    const float* __restrict__ W0, const float* __restrict__ W1, const float* __restrict__ W2,
    float* __restrict__ out0, float* __restrict__ out1, float* __restrict__ out2,
    const float* __restrict__ Sin, const float* __restrict__ gamma, const float* __restrict__ beta,
    float inv_n, float* __restrict__ Sout)
{
    const float* W = (blockIdx.y == 0) ? W0 : ((blockIdx.y == 1) ? W1 : W2);
    float* out     = (blockIdx.y == 0) ? out0 : ((blockIdx.y == 1) ? out1 : out2);

    __shared__ float Wl[64][64];
    __shared__ float inl[64][65];
    __shared__ float scl[64], shl[64];
    __shared__ float ssum[64], ssq[64];

    const int t = threadIdx.x;
    if (t < 64) {
        if (TRN) { float sc, sh; bn_coeff(Sin, 64, t, gamma, beta, inv_n, sc, sh); scl[t] = sc; shl[t] = sh; }
        ssum[t] = 0.f; ssq[t] = 0.f;
    }
#pragma unroll
    for (int i = 0; i < 16; i++) { int idx = t + i * 256; Wl[idx >> 6][idx & 63] = W[idx]; }
    __syncthreads();

    const int rbase = blockIdx.x * 64;
    {
        const int d = t & 63;
        float sc = 0.f, sh = 0.f;
        if (TRN) { sc = scl[d]; sh = shl[d]; }
#pragma unroll
        for (int i = 0; i < 16; i++) {
            int r = (t >> 6) + i * 4;
            float v = in[(size_t)(rbase + r) * 64 + d];
            if (TRN) v = fmaxf(fmaf(v, sc, sh), 0.f);
            inl[r][d] = v;
        }
    }
    __syncthreads();

    const int c0 = (t & 15) * 4, r0 = (t >> 4) * 4;
    float acc[4][4] = {};
#pragma unroll 16
    for (int d = 0; d < 64; d++) {
        float4 w4 = *(const float4*)&Wl[d][c0];
#pragma unroll
        for (int i = 0; i < 4; i++) {
            float h = inl[r0 + i][d];
            acc[i][0] = fmaf(h, w4.x, acc[i][0]);
            acc[i][1] = fmaf(h, w4.y, acc[i][1]);
            acc[i][2] = fmaf(h, w4.z, acc[i][2]);
            acc[i][3] = fmaf(h, w4.w, acc[i][3]);
        }
    }
#pragma unroll
    for (int i = 0; i < 4; i++) {
        float4 o; o.x = acc[i][0]; o.y = acc[i][1]; o.z = acc[i][2]; o.w = acc[i][3];
        *(float4*)&out[(size_t)(rbase + r0 + i) * 64 + c0] = o;
    }
    if (Sout) {
#pragma unroll
        for (int j = 0; j < 4; j++) {
            float s  = acc[0][j] + acc[1][j] + acc[2][j] + acc[3][j];
            float qv = acc[0][j] * acc[0][j] + acc[1][j] * acc[1][j] + acc[2][j] * acc[2][j] + acc[3][j] * acc[3][j];
            atomicAdd(&ssum[c0 + j], s);
            atomicAdd(&ssq[c0 + j], qv);
        }
        __syncthreads();
        if (t < 64) { atomicAdd(&Sout[t], ssum[t]); atomicAdd(&Sout[64 + t], ssq[t]); }
    }
}

// q = (pos[dst]-pos[src]) @ Wp1 + bp1, stored SoA; raw stats (3 cols) — 6 atomics/BLOCK.
__global__ __launch_bounds__(256) void edge_q_k(
    const float* __restrict__ pos, const int* __restrict__ src,
    const float* __restrict__ Wp1, const float* __restrict__ bp1,
    float* __restrict__ q0, float* __restrict__ q1, float* __restrict__ q2,
    float* __restrict__ Sq)
{
    float w00 = Wp1[0], w01 = Wp1[1], w02 = Wp1[2];
    float w10 = Wp1[3], w11 = Wp1[4], w12 = Wp1[5];
    float w20 = Wp1[6], w21 = Wp1[7], w22 = Wp1[8];
    float c0 = bp1[0], c1 = bp1[1], c2 = bp1[2];
    float s0 = 0, s1 = 0, s2 = 0, p0 = 0, p1 = 0, p2 = 0;
    for (int e = blockIdx.x * blockDim.x + threadIdx.x; e < EE; e += gridDim.x * blockDim.x) {
        int sj = src[e]; int di = e >> 4;
        float r0 = pos[di * 3 + 0] - pos[sj * 3 + 0];
        float r1 = pos[di * 3 + 1] - pos[sj * 3 + 1];
        float r2 = pos[di * 3 + 2] - pos[sj * 3 + 2];
        float v0 = c0 + r0 * w00 + r1 * w10 + r2 * w20;
        float v1 = c1 + r0 * w01 + r1 * w11 + r2 * w21;
        float v2 = c2 + r0 * w02 + r1 * w12 + r2 * w22;
        q0[e] = v0; q1[e] = v1; q2[e] = v2;
        s0 += v0; s1 += v1; s2 += v2;
        p0 += v0 * v0; p1 += v1 * v1; p2 += v2 * v2;
    }
#pragma unroll
    for (int o = 32; o > 0; o >>= 1) {
        s0 += __shfl_down(s0, o); s1 += __shfl_down(s1, o); s2 += __shfl_down(s2, o);
        p0 += __shfl_down(p0, o); p1 += __shfl_down(p1, o); p2 += __shfl_down(p2, o);
    }
    __shared__ float sred[4][6];
    const int w = threadIdx.x >> 6;
    if ((threadIdx.x & 63) == 0) {
        sred[w][0] = s0; sred[w][1] = s1; sred[w][2] = s2;
        sred[w][3] = p0; sred[w][4] = p1; sred[w][5] = p2;
    }
    __syncthreads();
    if (threadIdx.x < 6) {
        float v = sred[0][threadIdx.x] + sred[1][threadIdx.x] + sred[2][threadIdx.x] + sred[3][threadIdx.x];
        atomicAdd(&Sq[threadIdx.x], v);
    }
}

// Store-free raw column stats of a0 = a_dst[dst] - a_src[src] + delta  (64 cols over E rows).
__global__ __launch_bounds__(256) void edge_a0_k(
    const float* __restrict__ q0, const float* __restrict__ q1, const float* __restrict__ q2,
    const int* __restrict__ src,
    const float* __restrict__ adst, const float* __restrict__ asrc,
    const float* __restrict__ Wp2, const float* __restrict__ bp2,
    const float* __restrict__ Sq, const float* __restrict__ gp, const float* __restrict__ bp_,
    float* __restrict__ Sa0)
{
    const int lane = threadIdx.x & 63;
    const int wid  = (blockIdx.x * blockDim.x + threadIdx.x) >> 6;
    const int nw   = (gridDim.x * blockDim.x) >> 6;
    const float inv_e = 1.0f / (float)EE;
    float sc30, sh30, sc31, sh31, sc32, sh32;
    bn_coeff(Sq, 3, 0, gp, bp_, inv_e, sc30, sh30);
    bn_coeff(Sq, 3, 1, gp, bp_, inv_e, sc31, sh31);
    bn_coeff(Sq, 3, 2, gp, bp_, inv_e, sc32, sh32);
    float w0 = Wp2[lane], w1 = Wp2[64 + lane], w2 = Wp2[128 + lane], bd = bp2[lane];
    float s = 0.f, sq = 0.f;
    for (int e = wid; e < EE; e += nw) {
        float ph0 = fmaxf(fmaf(q0[e], sc30, sh30), 0.f);
        float ph1 = fmaxf(fmaf(q1[e], sc31, sh31), 0.f);
        float ph2 = fmaxf(fmaf(q2[e], sc32, sh32), 0.f);
        float dl  = bd + ph0 * w0 + ph1 * w1 + ph2 * w2;
        float a0  = adst[(size_t)(e >> 4) * 64 + lane] - asrc[(size_t)src[e] * 64 + lane] + dl;
        s += a0; sq += a0 * a0;
    }
    __shared__ float ls[64], lq[64];
    if (threadIdx.x < 64) { ls[threadIdx.x] = 0.f; lq[threadIdx.x] = 0.f; }
    __syncthreads();
    atomicAdd(&ls[lane], s); atomicAdd(&lq[lane], sq);
    __syncthreads();
    if (threadIdx.x < 64) { atomicAdd(&Sa0[threadIdx.x], ls[threadIdx.x]); atomicAdd(&Sa0[64 + threadIdx.x], lq[threadIdx.x]); }
}

// t = relu(bn(a0)) @ Wa1 + ba1  [E,8]; a1 recomputed into LDS; raw stats (8 cols).
__global__ __launch_bounds__(128) void edge_t_k(
    const float* __restrict__ q0, const float* __restrict__ q1, const float* __restrict__ q2,
    const int* __restrict__ src,
    const float* __restrict__ adst, const float* __restrict__ asrc,
    const float* __restrict__ Wp2, const float* __restrict__ bp2,
    const float* __restrict__ Sq, const float* __restrict__ gp, const float* __restrict__ bp_,
    const float* __restrict__ Sa0, const float* __restrict__ ga0, const float* __restrict__ ba0,
    const float* __restrict__ Wa1, const float* __restrict__ ba1,
    float* __restrict__ tout, float* __restrict__ St)
{
    __shared__ float a1l[128][65];
    __shared__ float wl[64][8];
    __shared__ float red[16];
    const int t = threadIdx.x;
    const int lane = t & 63;
    const float inv_e = 1.0f / (float)EE;
    float sc30, sh30, sc31, sh31, sc32, sh32;
    bn_coeff(Sq, 3, 0, gp, bp_, inv_e, sc30, sh30);
    bn_coeff(Sq, 3, 1, gp, bp_, inv_e, sc31, sh31);
    bn_coeff(Sq, 3, 2, gp, bp_, inv_e, sc32, sh32);
    float scA, shA; bn_coeff(Sa0, 64, lane, ga0, ba0, inv_e, scA, shA);
    float w0 = Wp2[lane], w1 = Wp2[64 + lane], w2 = Wp2[128 + lane], bd = bp2[lane];
    for (int i = t; i < 512; i += 128) wl[i >> 3][i & 7] = Wa1[i];
    if (t < 16) red[t] = 0.f;
    float b8[8];
#pragma unroll
    for (int k = 0; k < 8; k++) b8[k] = ba1[k];
    float ss[8] = {}, sp[8] = {};

    for (int it = 0; it < 8; ++it) {
        __syncthreads();
        const int e0 = (blockIdx.x + it * 625) * 128;
        // stage a1 tile: thread covers fixed d=lane, edges (t>>6)+i*2
        for (int i = 0; i < 64; i++) {
            int el = (t >> 6) + i * 2;
            int e  = e0 + el;
            float ph0 = fmaxf(fmaf(q0[e], sc30, sh30), 0.f);
            float ph1 = fmaxf(fmaf(q1[e], sc31, sh31), 0.f);
            float ph2 = fmaxf(fmaf(q2[e], sc32, sh32), 0.f);
            float dl  = bd + ph0 * w0 + ph1 * w1 + ph2 * w2;
            float a0  = adst[(size_t)(e >> 4) * 64 + lane] - asrc[(size_t)src[e] * 64 + lane] + dl;
            a1l[el][lane] = fmaxf(fmaf(a0, scA, shA), 0.f);
        }
        __syncthreads();
        {
            int e = e0 + t;
            float acc[8];
#pragma unroll
            for (int k = 0; k < 8; k++) acc[k] = b8[k];
#pragma unroll 8
            for (int dd = 0; dd < 64; dd++) {
                float a = a1l[t][dd];
                float4 lo = *(const float4*)&wl[dd][0];
                float4 hi = *(const float4*)&wl[dd][4];
                acc[0] = fmaf(a, lo.x, acc[0]); acc[1] = fmaf(a, lo.y, acc[1]);
                acc[2] = fmaf(a, lo.z, acc[2]); acc[3] = fmaf(a, lo.w, acc[3]);
                acc[4] = fmaf(a, hi.x, acc[4]); acc[5] = fmaf(a, hi.y, acc[5]);
                acc[6] = fmaf(a, hi.z, acc[6]); acc[7] = fmaf(a, hi.w, acc[7]);
            }
            float4 o0, o1;
            o0.x = acc[0]; o0.y = acc[1]; o0.z = acc[2]; o0.w = acc[3];
            o1.x = acc[4]; o1.y = acc[5]; o1.z = acc[6]; o1.w = acc[7];
            *(float4*)&tout[(size_t)e * 8]     = o0;
            *(float4*)&tout[(size_t)e * 8 + 4] = o1;
#pragma unroll
            for (int k = 0; k < 8; k++) { ss[k] += acc[k]; sp[k] += acc[k] * acc[k]; }
        }
    }
#pragma unroll
    for (int o = 32; o > 0; o >>= 1) {
#pragma unroll
        for (int k = 0; k < 8; k++) { ss[k] += __shfl_down(ss[k], o); sp[k] += __shfl_down(sp[k], o); }
    }
    if (lane == 0) {
#pragma unroll
        for (int k = 0; k < 8; k++) { atomicAdd(&red[k], ss[k]); atomicAdd(&red[8 + k], sp[k]); }
    }
    __syncthreads();
    if (t < 16) atomicAdd(&St[t], red[t]);
}

// Per-node (wave) fused: a2=relu(bn(t)); a3=a2@Wa2+ba2; softmax over 16 edges; agg; raw stats.
__global__ __launch_bounds__(256) void edge_final_k(
    const float* __restrict__ tin,
    const float* __restrict__ q0, const float* __restrict__ q1, const float* __restrict__ q2,
    const int* __restrict__ src, const float* __restrict__ vv,
    const float* __restrict__ Wp2, const float* __restrict__ bp2,
    const float* __restrict__ Sq, const float* __restrict__ gp, const float* __restrict__ bp_,
    const float* __restrict__ St, const float* __restrict__ ga1, const float* __restrict__ bb1,
    const float* __restrict__ Wa2, const float* __restrict__ ba2,
    float* __restrict__ agg, float* __restrict__ Sagg)
{
    const int t = threadIdx.x, lane = t & 63, w = t >> 6;
    const float inv_e = 1.0f / (float)EE;
    float sc3[3], sh3[3];
#pragma unroll
    for (int k = 0; k < 3; k++) bn_coeff(Sq, 3, k, gp, bp_, inv_e, sc3[k], sh3[k]);
    float sc8[8], sh8[8];
#pragma unroll
    for (int k = 0; k < 8; k++) bn_coeff(St, 8, k, ga1, bb1, inv_e, sc8[k], sh8[k]);
    float wa[8];
#pragma unroll
    for (int k = 0; k < 8; k++) wa[k] = Wa2[k * 64 + lane];
    float bad = ba2[lane];
    float wp0 = Wp2[lane], wp1 = Wp2[64 + lane], wp2 = Wp2[128 + lane];
    float bpd = bp2[lane];
    float ssum = 0.f, ssq = 0.f;

    for (int nn = 0; nn < 16; nn++) {
        int i = blockIdx.x * 64 + nn * 4 + w;
        float ax[16], dl[16], vs[16];
        float m = -3.0e38f;
#pragma unroll
        for (int j = 0; j < 16; j++) {
            int e = i * 16 + j;
            const float4* tp = (const float4*)(tin + (size_t)e * 8);
            float4 ta = tp[0], tb = tp[1];
            float a20 = fmaxf(fmaf(ta.x, sc8[0], sh8[0]), 0.f);
            float a21 = fmaxf(fmaf(ta.y, sc8[1], sh8[1]), 0.f);
            float a22 = fmaxf(fmaf(ta.z, sc8[2], sh8[2]), 0.f);
            float a23 = fmaxf(fmaf(ta.w, sc8[3], sh8[3]), 0.f);
            float a24 = fmaxf(fmaf(tb.x, sc8[4], sh8[4]), 0.f);
            float a25 = fmaxf(fmaf(tb.y, sc8[5], sh8[5]), 0.f);
            float a26 = fmaxf(fmaf(tb.z, sc8[6], sh8[6]), 0.f);
            float a27 = fmaxf(fmaf(tb.w, sc8[7], sh8[7]), 0.f);
            float a = bad;
            a = fmaf(a20, wa[0], a); a = fmaf(a21, wa[1], a);
            a = fmaf(a22, wa[2], a); a = fmaf(a23, wa[3], a);
            a = fmaf(a24, wa[4], a); a = fmaf(a25, wa[5], a);
            a = fmaf(a26, wa[6], a); a = fmaf(a27, wa[7], a);
            float ph0 = fmaxf(fmaf(q0[e], sc3[0], sh3[0]), 0.f);
            float ph1 = fmaxf(fmaf(q1[e], sc3[1], sh3[1]), 0.f);
            float ph2 = fmaxf(fmaf(q2[e], sc3[2], sh3[2]), 0.f);
            dl[j] = bpd + ph0 * wp0 + ph1 * wp1 + ph2 * wp2;
            vs[j] = vv[(size_t)src[e] * 64 + lane];
            ax[j] = a; m = fmaxf(m, a);
        }
        float s = 0.f;
#pragma unroll
        for (int j = 0; j < 16; j++) { ax[j] = __expf(ax[j] - m); s += ax[j]; }
        float inv = 1.0f / (s + 1e-16f);
        float ag = 0.f;
#pragma unroll
        for (int j = 0; j < 16; j++) ag += ax[j] * (vs[j] + dl[j]);
        ag *= inv;
        agg[(size_t)i * 64 + lane] = ag;
        ssum += ag; ssq += ag * ag;
    }
    __shared__ float ls[64], lq[64];
    if (t < 64) { ls[t] = 0.f; lq[t] = 0.f; }
    __syncthreads();
    atomicAdd(&ls[lane], ssum); atomicAdd(&lq[lane], ssq);
    __syncthreads();
    if (t < 64) { atomicAdd(&Sagg[t], ls[t]); atomicAdd(&Sagg[64 + t], lq[t]); }
}

// out = relu(bn(t2,g3,b3) + x)
__global__ __launch_bounds__(256) void final_k(
    const float* __restrict__ t2, const float* __restrict__ x,
    const float* __restrict__ St2, const float* __restrict__ g3, const float* __restrict__ b3,
    float* __restrict__ out)
{
    __shared__ float scl[64], shl[64];
    const int t = threadIdx.x;
    if (t < 64) { float sc, sh; bn_coeff(St2, 64, t, g3, b3, 1.0f / (float)NN, sc, sh); scl[t] = sc; shl[t] = sh; }
    __syncthreads();
    int idx = blockIdx.x * 256 + t;          // float4 index; NN*64/4 = 640000 exactly
    int c0 = (idx & 15) * 4;
    const float4 a = *(const float4*)&t2[(size_t)idx * 4];
    const float4 b = *(const float4*)&x[(size_t)idx * 4];
    float4 o;
    o.x = fmaxf(fmaf(a.x, scl[c0 + 0], shl[c0 + 0]) + b.x, 0.f);
    o.y = fmaxf(fmaf(a.y, scl[c0 + 1], shl[c0 + 1]) + b.y, 0.f);
    o.z = fmaxf(fmaf(a.z, scl[c0 + 2], shl[c0 + 2]) + b.z, 0.f);
    o.w = fmaxf(fmaf(a.w, scl[c0 + 3], shl[c0 + 3]) + b.w, 0.f);
    *(float4*)&out[(size_t)idx * 4] = o;
}

extern "C" void kernel_launch(void* const* d_in, const int* in_sizes, int n_in,
                              void* d_out, int out_size, void* d_ws, size_t ws_size,
                              hipStream_t stream)
{
    const float* x    = (const float*)d_in[0];
    const float* pos  = (const float*)d_in[1];
    const int*   src  = (const int*)d_in[2];      // edge_index[0]; dst[e] == e>>4 by construction
    const float* W_in = (const float*)d_in[3];
    const float* g1   = (const float*)d_in[4];
    const float* b1   = (const float*)d_in[5];
    const float* W_v  = (const float*)d_in[6];
    const float* W_src= (const float*)d_in[7];
    const float* W_dst= (const float*)d_in[8];
    const float* Wp1  = (const float*)d_in[9];
    const float* bp1  = (const float*)d_in[10];
    const float* gp   = (const float*)d_in[11];
    const float* bp_  = (const float*)d_in[12];
    const float* Wp2  = (const float*)d_in[13];
    const float* bp2  = (const float*)d_in[14];
    const float* ga0  = (const float*)d_in[15];
    const float* ba0  = (const float*)d_in[16];
    const float* Wa1  = (const float*)d_in[17];
    const float* ba1  = (const float*)d_in[18];
    const float* ga1  = (const float*)d_in[19];
    const float* bb1  = (const float*)d_in[20];
    const float* Wa2  = (const float*)d_in[21];
    const float* ba2  = (const float*)d_in[22];
    const float* g2   = (const float*)d_in[23];
    const float* b2   = (const float*)d_in[24];
    const float* W_out= (const float*)d_in[25];
    const float* g3   = (const float*)d_in[26];
    const float* b3   = (const float*)d_in[27];
    float* out = (float*)d_out;

    float* wsf   = (float*)d_ws;
    float* S_t1  = wsf;          // 128
    float* S_q   = wsf + 128;    // 6 used
    float* S_a0  = wsf + 192;    // 128
    float* S_t   = wsf + 320;    // 16 used
    float* S_agg = wsf + 384;    // 128
    float* S_t2  = wsf + 512;    // 128
    const size_t N64 = (size_t)NN * 64;
    float* t1   = wsf + 1024;
    float* asrc = t1 + N64;
    float* adst = asrc + N64;
    float* vv   = adst + N64;
    float* q0   = vv + N64;
    float* q1   = q0 + EE;
    float* q2   = q1 + EE;
    float* tt   = q2 + EE;       // [E,8]
    float* agg  = t1;            // alias: t1 dead after gemm #2
    float* t2   = asrc;          // alias: asrc dead after edge_t

    hipMemsetAsync(wsf, 0, 1024 * sizeof(float), stream);

    // t1 = x @ W_in (+stats)
    gemm64_k<0><<<dim3(625, 1), 256, 0, stream>>>(x, W_in, W_in, W_in, t1, t1, t1,
                                                  nullptr, nullptr, nullptr, 0.f, S_t1);
    // h = relu(bn(t1)); {asrc,adst,vv} = h @ {W_src,W_dst,W_v}
    gemm64_k<1><<<dim3(625, 3), 256, 0, stream>>>(t1, W_src, W_dst, W_v, asrc, adst, vv,
                                                  S_t1, g1, b1, 1.0f / (float)NN, nullptr);
    // q = (pos[dst]-pos[src]) @ Wp1 + bp1 (+stats3) — 6 atomics/block, 256 blocks
    edge_q_k<<<256, 256, 0, stream>>>(pos, src, Wp1, bp1, q0, q1, q2, S_q);
    // raw stats of a0 (store-free) — 256 blocks
    edge_a0_k<<<256, 256, 0, stream>>>(q0, q1, q2, src, adst, asrc, Wp2, bp2, S_q, gp, bp_, S_a0);
    // t = relu(bn(a0)) @ Wa1 + ba1 (+stats8) — 625 blocks × 8 tiles
    edge_t_k<<<625, 128, 0, stream>>>(q0, q1, q2, src, adst, asrc, Wp2, bp2, S_q, gp, bp_,
                                      S_a0, ga0, ba0, Wa1, ba1, tt, S_t);
    // a2,a3,softmax,agg (+stats) — 625 blocks × 64 nodes
    edge_final_k<<<625, 256, 0, stream>>>(tt, q0, q1, q2, src, vv, Wp2, bp2, S_q, gp, bp_,
                                          S_t, ga1, bb1, Wa2, ba2, agg, S_agg);
    // t2 = relu(bn(agg,g2,b2)) @ W_out (+stats)
    gemm64_k<1><<<dim3(625, 1), 256, 0, stream>>>(agg, W_out, W_out, W_out, t2, t2, t2,
                                                  S_agg, g2, b2, 1.0f / (float)NN, S_t2);
    // out = relu(bn(t2,g3,b3) + x)
    final_k<<<2500, 256, 0, stream>>>(t2, x, S_t2, g3, b3, out);
}

// Round 7
// 446.413 us; speedup vs baseline: 1.7886x; 1.5613x over previous
//
#include <hip/hip_runtime.h>

#define NN 40000
#define DDIM 64
#define KE 16
#define EE 640000
#define BNEPS 1e-5f

// Finalize BN coefficients from raw sums: stats layout [sum[C], sumsq[C]].
__device__ __forceinline__ void bn_coeff(const float* __restrict__ S, int C, int c,
                                         const float* __restrict__ g, const float* __restrict__ b,
                                         float inv_n, float& sc, float& sh)
{
    float m   = S[c] * inv_n;
    float var = S[C + c] * inv_n - m * m;
    float r   = rsqrtf(var + BNEPS);
    sc = g[c] * r;
    sh = b[c] - m * sc;
}

// out[r][c] = sum_d f(in[r][d]) * W[d][c], 64x64 W, optional BN+ReLU input transform,
// optional raw column-stats accumulation on the output.
template<int TRN>
__global__ __launch_bounds__(256) void gemm64_k(
    const float* __restrict__ in,
    const float* __restrict__ W0, const float* __restrict__ W1, const float* __restrict__ W2,
    float* __restrict__ out0, float* __restrict__ out1, float* __restrict__ out2,
    const float* __restrict__ Sin, const float* __restrict__ gamma, const float* __restrict__ beta,
    float inv_n, float* __restrict__ Sout)
{
    const float* W = (blockIdx.y == 0) ? W0 : ((blockIdx.y == 1) ? W1 : W2);
    float* out     = (blockIdx.y == 0) ? out0 : ((blockIdx.y == 1) ? out1 : out2);

    __shared__ float Wl[64][64];
    __shared__ float inl[64][65];
    __shared__ float scl[64], shl[64];
    __shared__ float ssum[64], ssq[64];

    const int t = threadIdx.x;
    if (t < 64) {
        if (TRN) { float sc, sh; bn_coeff(Sin, 64, t, gamma, beta, inv_n, sc, sh); scl[t] = sc; shl[t] = sh; }
        ssum[t] = 0.f; ssq[t] = 0.f;
    }
#pragma unroll
    for (int i = 0; i < 16; i++) { int idx = t + i * 256; Wl[idx >> 6][idx & 63] = W[idx]; }
    __syncthreads();

    const int rbase = blockIdx.x * 64;
    {
        const int d = t & 63;
        float sc = 0.f, sh = 0.f;
        if (TRN) { sc = scl[d]; sh = shl[d]; }
#pragma unroll
        for (int i = 0; i < 16; i++) {
            int r = (t >> 6) + i * 4;
            float v = in[(size_t)(rbase + r) * 64 + d];
            if (TRN) v = fmaxf(fmaf(v, sc, sh), 0.f);
            inl[r][d] = v;
        }
    }
    __syncthreads();

    const int c0 = (t & 15) * 4, r0 = (t >> 4) * 4;
    float acc[4][4] = {};
#pragma unroll 16
    for (int d = 0; d < 64; d++) {
        float4 w4 = *(const float4*)&Wl[d][c0];
#pragma unroll
        for (int i = 0; i < 4; i++) {
            float h = inl[r0 + i][d];
            acc[i][0] = fmaf(h, w4.x, acc[i][0]);
            acc[i][1] = fmaf(h, w4.y, acc[i][1]);
            acc[i][2] = fmaf(h, w4.z, acc[i][2]);
            acc[i][3] = fmaf(h, w4.w, acc[i][3]);
        }
    }
#pragma unroll
    for (int i = 0; i < 4; i++) {
        float4 o; o.x = acc[i][0]; o.y = acc[i][1]; o.z = acc[i][2]; o.w = acc[i][3];
        *(float4*)&out[(size_t)(rbase + r0 + i) * 64 + c0] = o;
    }
    if (Sout) {
#pragma unroll
        for (int j = 0; j < 4; j++) {
            float s  = acc[0][j] + acc[1][j] + acc[2][j] + acc[3][j];
            float qv = acc[0][j] * acc[0][j] + acc[1][j] * acc[1][j] + acc[2][j] * acc[2][j] + acc[3][j] * acc[3][j];
            atomicAdd(&ssum[c0 + j], s);
            atomicAdd(&ssq[c0 + j], qv);
        }
        __syncthreads();
        if (t < 64) { atomicAdd(&Sout[t], ssum[t]); atomicAdd(&Sout[64 + t], ssq[t]); }
    }
}

// q = (pos[dst]-pos[src]) @ Wp1 + bp1, stored SoA; raw stats (3 cols) — 6 atomics/BLOCK.
__global__ __launch_bounds__(256) void edge_q_k(
    const float* __restrict__ pos, const int* __restrict__ src,
    const float* __restrict__ Wp1, const float* __restrict__ bp1,
    float* __restrict__ q0, float* __restrict__ q1, float* __restrict__ q2,
    float* __restrict__ Sq)
{
    float w00 = Wp1[0], w01 = Wp1[1], w02 = Wp1[2];
    float w10 = Wp1[3], w11 = Wp1[4], w12 = Wp1[5];
    float w20 = Wp1[6], w21 = Wp1[7], w22 = Wp1[8];
    float c0 = bp1[0], c1 = bp1[1], c2 = bp1[2];
    float s0 = 0, s1 = 0, s2 = 0, p0 = 0, p1 = 0, p2 = 0;
    for (int e = blockIdx.x * blockDim.x + threadIdx.x; e < EE; e += gridDim.x * blockDim.x) {
        int sj = src[e]; int di = e >> 4;
        float r0 = pos[di * 3 + 0] - pos[sj * 3 + 0];
        float r1 = pos[di * 3 + 1] - pos[sj * 3 + 1];
        float r2 = pos[di * 3 + 2] - pos[sj * 3 + 2];
        float v0 = c0 + r0 * w00 + r1 * w10 + r2 * w20;
        float v1 = c1 + r0 * w01 + r1 * w11 + r2 * w21;
        float v2 = c2 + r0 * w02 + r1 * w12 + r2 * w22;
        q0[e] = v0; q1[e] = v1; q2[e] = v2;
        s0 += v0; s1 += v1; s2 += v2;
        p0 += v0 * v0; p1 += v1 * v1; p2 += v2 * v2;
    }
#pragma unroll
    for (int o = 32; o > 0; o >>= 1) {
        s0 += __shfl_down(s0, o); s1 += __shfl_down(s1, o); s2 += __shfl_down(s2, o);
        p0 += __shfl_down(p0, o); p1 += __shfl_down(p1, o); p2 += __shfl_down(p2, o);
    }
    __shared__ float sred[4][6];
    const int w = threadIdx.x >> 6;
    if ((threadIdx.x & 63) == 0) {
        sred[w][0] = s0; sred[w][1] = s1; sred[w][2] = s2;
        sred[w][3] = p0; sred[w][4] = p1; sred[w][5] = p2;
    }
    __syncthreads();
    if (threadIdx.x < 6) {
        float v = sred[0][threadIdx.x] + sred[1][threadIdx.x] + sred[2][threadIdx.x] + sred[3][threadIdx.x];
        atomicAdd(&Sq[threadIdx.x], v);
    }
}

// Store-free raw column stats of a0 = a_dst[dst] - a_src[src] + delta  (64 cols over E rows).
// Node-per-wave: adst row loaded once/node; src+q broadcast via shfl; 16 gathers in flight.
__global__ __launch_bounds__(256) void edge_a0_k(
    const float* __restrict__ q0, const float* __restrict__ q1, const float* __restrict__ q2,
    const int* __restrict__ src,
    const float* __restrict__ adst, const float* __restrict__ asrc,
    const float* __restrict__ Wp2, const float* __restrict__ bp2,
    const float* __restrict__ Sq, const float* __restrict__ gp, const float* __restrict__ bp_,
    float* __restrict__ Sa0)
{
    const int lane = threadIdx.x & 63;
    const int wv   = blockIdx.x * (blockDim.x >> 6) + (threadIdx.x >> 6);
    const int nwv  = gridDim.x * (blockDim.x >> 6);
    const float inv_e = 1.0f / (float)EE;
    float sc30, sh30, sc31, sh31, sc32, sh32;
    bn_coeff(Sq, 3, 0, gp, bp_, inv_e, sc30, sh30);
    bn_coeff(Sq, 3, 1, gp, bp_, inv_e, sc31, sh31);
    bn_coeff(Sq, 3, 2, gp, bp_, inv_e, sc32, sh32);
    float w0 = Wp2[lane], w1 = Wp2[64 + lane], w2 = Wp2[128 + lane], bd = bp2[lane];
    float s = 0.f, sq = 0.f;
    for (int i = wv; i < NN; i += nwv) {
        const int e0 = i << 4;
        float ad  = adst[(size_t)i * 64 + lane];
        int   sv  = src[e0 + (lane & 15)];
        float qv0 = q0[e0 + (lane & 15)];
        float qv1 = q1[e0 + (lane & 15)];
        float qv2 = q2[e0 + (lane & 15)];
        int sidx[16];
#pragma unroll
        for (int k = 0; k < 16; k++) sidx[k] = __shfl(sv, k);
        float av[16];
#pragma unroll
        for (int k = 0; k < 16; k++) av[k] = asrc[(size_t)sidx[k] * 64 + lane];
#pragma unroll
        for (int k = 0; k < 16; k++) {
            float ph0 = fmaxf(fmaf(__shfl(qv0, k), sc30, sh30), 0.f);
            float ph1 = fmaxf(fmaf(__shfl(qv1, k), sc31, sh31), 0.f);
            float ph2 = fmaxf(fmaf(__shfl(qv2, k), sc32, sh32), 0.f);
            float dl  = bd + ph0 * w0 + ph1 * w1 + ph2 * w2;
            float a0v = ad - av[k] + dl;
            s += a0v; sq += a0v * a0v;
        }
    }
    __shared__ float ls[64], lq[64];
    if (threadIdx.x < 64) { ls[threadIdx.x] = 0.f; lq[threadIdx.x] = 0.f; }
    __syncthreads();
    atomicAdd(&ls[lane], s); atomicAdd(&lq[lane], sq);
    __syncthreads();
    if (threadIdx.x < 64) { atomicAdd(&Sa0[threadIdx.x], ls[threadIdx.x]); atomicAdd(&Sa0[64 + threadIdx.x], lq[threadIdx.x]); }
}

// t = relu(bn(a0)) @ Wa1 + ba1  [E,8]; a1 recomputed into LDS; raw stats (8 cols).
__global__ __launch_bounds__(128) void edge_t_k(
    const float* __restrict__ q0, const float* __restrict__ q1, const float* __restrict__ q2,
    const int* __restrict__ src,
    const float* __restrict__ adst, const float* __restrict__ asrc,
    const float* __restrict__ Wp2, const float* __restrict__ bp2,
    const float* __restrict__ Sq, const float* __restrict__ gp, const float* __restrict__ bp_,
    const float* __restrict__ Sa0, const float* __restrict__ ga0, const float* __restrict__ ba0,
    const float* __restrict__ Wa1, const float* __restrict__ ba1,
    float* __restrict__ tout, float* __restrict__ St)
{
    __shared__ float a1l[128][65];
    __shared__ float wl[64][8];
    __shared__ float red[16];
    const int t = threadIdx.x;
    const int lane = t & 63;
    const float inv_e = 1.0f / (float)EE;
    float sc30, sh30, sc31, sh31, sc32, sh32;
    bn_coeff(Sq, 3, 0, gp, bp_, inv_e, sc30, sh30);
    bn_coeff(Sq, 3, 1, gp, bp_, inv_e, sc31, sh31);
    bn_coeff(Sq, 3, 2, gp, bp_, inv_e, sc32, sh32);
    float scA, shA; bn_coeff(Sa0, 64, lane, ga0, ba0, inv_e, scA, shA);
    float w0 = Wp2[lane], w1 = Wp2[64 + lane], w2 = Wp2[128 + lane], bd = bp2[lane];
    for (int i = t; i < 512; i += 128) wl[i >> 3][i & 7] = Wa1[i];
    if (t < 16) red[t] = 0.f;
    float b8[8];
#pragma unroll
    for (int k = 0; k < 8; k++) b8[k] = ba1[k];
    float ss[8] = {}, sp[8] = {};

    for (int it = 0; it < 4; ++it) {
        __syncthreads();
        const int e0 = (blockIdx.x + it * 1250) * 128;
        // stage a1 tile: thread covers fixed d=lane, edges (t>>6)+i*2
        for (int i = 0; i < 64; i++) {
            int el = (t >> 6) + i * 2;
            int e  = e0 + el;
            float ph0 = fmaxf(fmaf(q0[e], sc30, sh30), 0.f);
            float ph1 = fmaxf(fmaf(q1[e], sc31, sh31), 0.f);
            float ph2 = fmaxf(fmaf(q2[e], sc32, sh32), 0.f);
            float dl  = bd + ph0 * w0 + ph1 * w1 + ph2 * w2;
            float a0  = adst[(size_t)(e >> 4) * 64 + lane] - asrc[(size_t)src[e] * 64 + lane] + dl;
            a1l[el][lane] = fmaxf(fmaf(a0, scA, shA), 0.f);
        }
        __syncthreads();
        {
            int e = e0 + t;
            float acc[8];
#pragma unroll
            for (int k = 0; k < 8; k++) acc[k] = b8[k];
#pragma unroll 8
            for (int dd = 0; dd < 64; dd++) {
                float a = a1l[t][dd];
                float4 lo = *(const float4*)&wl[dd][0];
                float4 hi = *(const float4*)&wl[dd][4];
                acc[0] = fmaf(a, lo.x, acc[0]); acc[1] = fmaf(a, lo.y, acc[1]);
                acc[2] = fmaf(a, lo.z, acc[2]); acc[3] = fmaf(a, lo.w, acc[3]);
                acc[4] = fmaf(a, hi.x, acc[4]); acc[5] = fmaf(a, hi.y, acc[5]);
                acc[6] = fmaf(a, hi.z, acc[6]); acc[7] = fmaf(a, hi.w, acc[7]);
            }
            float4 o0, o1;
            o0.x = acc[0]; o0.y = acc[1]; o0.z = acc[2]; o0.w = acc[3];
            o1.x = acc[4]; o1.y = acc[5]; o1.z = acc[6]; o1.w = acc[7];
            *(float4*)&tout[(size_t)e * 8]     = o0;
            *(float4*)&tout[(size_t)e * 8 + 4] = o1;
#pragma unroll
            for (int k = 0; k < 8; k++) { ss[k] += acc[k]; sp[k] += acc[k] * acc[k]; }
        }
    }
#pragma unroll
    for (int o = 32; o > 0; o >>= 1) {
#pragma unroll
        for (int k = 0; k < 8; k++) { ss[k] += __shfl_down(ss[k], o); sp[k] += __shfl_down(sp[k], o); }
    }
    if (lane == 0) {
#pragma unroll
        for (int k = 0; k < 8; k++) { atomicAdd(&red[k], ss[k]); atomicAdd(&red[8 + k], sp[k]); }
    }
    __syncthreads();
    if (t < 16) atomicAdd(&St[t], red[t]);
}

// Per-node (wave) fused: a2=relu(bn(t)); a3=a2@Wa2+ba2; softmax over 16 edges; agg; raw stats.
__global__ __launch_bounds__(256) void edge_final_k(
    const float* __restrict__ tin,
    const float* __restrict__ q0, const float* __restrict__ q1, const float* __restrict__ q2,
    const int* __restrict__ src, const float* __restrict__ vv,
    const float* __restrict__ Wp2, const float* __restrict__ bp2,
    const float* __restrict__ Sq, const float* __restrict__ gp, const float* __restrict__ bp_,
    const float* __restrict__ St, const float* __restrict__ ga1, const float* __restrict__ bb1,
    const float* __restrict__ Wa2, const float* __restrict__ ba2,
    float* __restrict__ agg, float* __restrict__ Sagg)
{
    const int t = threadIdx.x, lane = t & 63, w = t >> 6;
    const float inv_e = 1.0f / (float)EE;
    float sc3[3], sh3[3];
#pragma unroll
    for (int k = 0; k < 3; k++) bn_coeff(Sq, 3, k, gp, bp_, inv_e, sc3[k], sh3[k]);
    float sc8[8], sh8[8];
#pragma unroll
    for (int k = 0; k < 8; k++) bn_coeff(St, 8, k, ga1, bb1, inv_e, sc8[k], sh8[k]);
    float wa[8];
#pragma unroll
    for (int k = 0; k < 8; k++) wa[k] = Wa2[k * 64 + lane];
    float bad = ba2[lane];
    float wp0 = Wp2[lane], wp1 = Wp2[64 + lane], wp2 = Wp2[128 + lane];
    float bpd = bp2[lane];
    float ssum = 0.f, ssq = 0.f;

    for (int nn = 0; nn < 4; nn++) {
        int i = blockIdx.x * 16 + nn * 4 + w;
        float ax[16], dl[16], vs[16];
        float m = -3.0e38f;
#pragma unroll
        for (int j = 0; j < 16; j++) {
            int e = i * 16 + j;
            const float4* tp = (const float4*)(tin + (size_t)e * 8);
            float4 ta = tp[0], tb = tp[1];
            float a20 = fmaxf(fmaf(ta.x, sc8[0], sh8[0]), 0.f);
            float a21 = fmaxf(fmaf(ta.y, sc8[1], sh8[1]), 0.f);
            float a22 = fmaxf(fmaf(ta.z, sc8[2], sh8[2]), 0.f);
            float a23 = fmaxf(fmaf(ta.w, sc8[3], sh8[3]), 0.f);
            float a24 = fmaxf(fmaf(tb.x, sc8[4], sh8[4]), 0.f);
            float a25 = fmaxf(fmaf(tb.y, sc8[5], sh8[5]), 0.f);
            float a26 = fmaxf(fmaf(tb.z, sc8[6], sh8[6]), 0.f);
            float a27 = fmaxf(fmaf(tb.w, sc8[7], sh8[7]), 0.f);
            float a = bad;
            a = fmaf(a20, wa[0], a); a = fmaf(a21, wa[1], a);
            a = fmaf(a22, wa[2], a); a = fmaf(a23, wa[3], a);
            a = fmaf(a24, wa[4], a); a = fmaf(a25, wa[5], a);
            a = fmaf(a26, wa[6], a); a = fmaf(a27, wa[7], a);
            float ph0 = fmaxf(fmaf(q0[e], sc3[0], sh3[0]), 0.f);
            float ph1 = fmaxf(fmaf(q1[e], sc3[1], sh3[1]), 0.f);
            float ph2 = fmaxf(fmaf(q2[e], sc3[2], sh3[2]), 0.f);
            dl[j] = bpd + ph0 * wp0 + ph1 * wp1 + ph2 * wp2;
            vs[j] = vv[(size_t)src[e] * 64 + lane];
            ax[j] = a; m = fmaxf(m, a);
        }
        float s = 0.f;
#pragma unroll
        for (int j = 0; j < 16; j++) { ax[j] = __expf(ax[j] - m); s += ax[j]; }
        float inv = 1.0f / (s + 1e-16f);
        float ag = 0.f;
#pragma unroll
        for (int j = 0; j < 16; j++) ag += ax[j] * (vs[j] + dl[j]);
        ag *= inv;
        agg[(size_t)i * 64 + lane] = ag;
        ssum += ag; ssq += ag * ag;
    }
    __shared__ float ls[64], lq[64];
    if (t < 64) { ls[t] = 0.f; lq[t] = 0.f; }
    __syncthreads();
    atomicAdd(&ls[lane], ssum); atomicAdd(&lq[lane], ssq);
    __syncthreads();
    if (t < 64) { atomicAdd(&Sagg[t], ls[t]); atomicAdd(&Sagg[64 + t], lq[t]); }
}

// out = relu(bn(t2,g3,b3) + x)
__global__ __launch_bounds__(256) void final_k(
    const float* __restrict__ t2, const float* __restrict__ x,
    const float* __restrict__ St2, const float* __restrict__ g3, const float* __restrict__ b3,
    float* __restrict__ out)
{
    __shared__ float scl[64], shl[64];
    const int t = threadIdx.x;
    if (t < 64) { float sc, sh; bn_coeff(St2, 64, t, g3, b3, 1.0f / (float)NN, sc, sh); scl[t] = sc; shl[t] = sh; }
    __syncthreads();
    int idx = blockIdx.x * 256 + t;          // float4 index; NN*64/4 = 640000 exactly
    int c0 = (idx & 15) * 4;
    const float4 a = *(const float4*)&t2[(size_t)idx * 4];
    const float4 b = *(const float4*)&x[(size_t)idx * 4];
    float4 o;
    o.x = fmaxf(fmaf(a.x, scl[c0 + 0], shl[c0 + 0]) + b.x, 0.f);
    o.y = fmaxf(fmaf(a.y, scl[c0 + 1], shl[c0 + 1]) + b.y, 0.f);
    o.z = fmaxf(fmaf(a.z, scl[c0 + 2], shl[c0 + 2]) + b.z, 0.f);
    o.w = fmaxf(fmaf(a.w, scl[c0 + 3], shl[c0 + 3]) + b.w, 0.f);
    *(float4*)&out[(size_t)idx * 4] = o;
}

extern "C" void kernel_launch(void* const* d_in, const int* in_sizes, int n_in,
                              void* d_out, int out_size, void* d_ws, size_t ws_size,
                              hipStream_t stream)
{
    const float* x    = (const float*)d_in[0];
    const float* pos  = (const float*)d_in[1];
    const int*   src  = (const int*)d_in[2];      // edge_index[0]; dst[e] == e>>4 by construction
    const float* W_in = (const float*)d_in[3];
    const float* g1   = (const float*)d_in[4];
    const float* b1   = (const float*)d_in[5];
    const float* W_v  = (const float*)d_in[6];
    const float* W_src= (const float*)d_in[7];
    const float* W_dst= (const float*)d_in[8];
    const float* Wp1  = (const float*)d_in[9];
    const float* bp1  = (const float*)d_in[10];
    const float* gp   = (const float*)d_in[11];
    const float* bp_  = (const float*)d_in[12];
    const float* Wp2  = (const float*)d_in[13];
    const float* bp2  = (const float*)d_in[14];
    const float* ga0  = (const float*)d_in[15];
    const float* ba0  = (const float*)d_in[16];
    const float* Wa1  = (const float*)d_in[17];
    const float* ba1  = (const float*)d_in[18];
    const float* ga1  = (const float*)d_in[19];
    const float* bb1  = (const float*)d_in[20];
    const float* Wa2  = (const float*)d_in[21];
    const float* ba2  = (const float*)d_in[22];
    const float* g2   = (const float*)d_in[23];
    const float* b2   = (const float*)d_in[24];
    const float* W_out= (const float*)d_in[25];
    const float* g3   = (const float*)d_in[26];
    const float* b3   = (const float*)d_in[27];
    float* out = (float*)d_out;

    float* wsf   = (float*)d_ws;
    float* S_t1  = wsf;          // 128
    float* S_q   = wsf + 128;    // 6 used
    float* S_a0  = wsf + 192;    // 128
    float* S_t   = wsf + 320;    // 16 used
    float* S_agg = wsf + 384;    // 128
    float* S_t2  = wsf + 512;    // 128
    const size_t N64 = (size_t)NN * 64;
    float* t1   = wsf + 1024;
    float* asrc = t1 + N64;
    float* adst = asrc + N64;
    float* vv   = adst + N64;
    float* q0   = vv + N64;
    float* q1   = q0 + EE;
    float* q2   = q1 + EE;
    float* tt   = q2 + EE;       // [E,8]
    float* agg  = t1;            // alias: t1 dead after gemm #2
    float* t2   = asrc;          // alias: asrc dead after edge_t

    hipMemsetAsync(wsf, 0, 1024 * sizeof(float), stream);

    // t1 = x @ W_in (+stats)
    gemm64_k<0><<<dim3(625, 1), 256, 0, stream>>>(x, W_in, W_in, W_in, t1, t1, t1,
                                                  nullptr, nullptr, nullptr, 0.f, S_t1);
    // h = relu(bn(t1)); {asrc,adst,vv} = h @ {W_src,W_dst,W_v}
    gemm64_k<1><<<dim3(625, 3), 256, 0, stream>>>(t1, W_src, W_dst, W_v, asrc, adst, vv,
                                                  S_t1, g1, b1, 1.0f / (float)NN, nullptr);
    // q = (pos[dst]-pos[src]) @ Wp1 + bp1 (+stats3) — 6 atomics/block
    edge_q_k<<<256, 256, 0, stream>>>(pos, src, Wp1, bp1, q0, q1, q2, S_q);
    // raw stats of a0 (store-free) — node-per-wave, 2048 blocks for latency hiding
    edge_a0_k<<<2048, 256, 0, stream>>>(q0, q1, q2, src, adst, asrc, Wp2, bp2, S_q, gp, bp_, S_a0);
    // t = relu(bn(a0)) @ Wa1 + ba1 (+stats8)
    edge_t_k<<<1250, 128, 0, stream>>>(q0, q1, q2, src, adst, asrc, Wp2, bp2, S_q, gp, bp_,
                                       S_a0, ga0, ba0, Wa1, ba1, tt, S_t);
    // a2,a3,softmax,agg (+stats)
    edge_final_k<<<2500, 256, 0, stream>>>(tt, q0, q1, q2, src, vv, Wp2, bp2, S_q, gp, bp_,
                                           S_t, ga1, bb1, Wa2, ba2, agg, S_agg);
    // t2 = relu(bn(agg,g2,b2)) @ W_out (+stats)
    gemm64_k<1><<<dim3(625, 1), 256, 0, stream>>>(agg, W_out, W_out, W_out, t2, t2, t2,
                                                  S_agg, g2, b2, 1.0f / (float)NN, S_t2);
    // out = relu(bn(t2,g3,b3) + x)
    final_k<<<2500, 256, 0, stream>>>(t2, x, S_t2, g3, b3, out);
}

// Round 9
// 358.746 us; speedup vs baseline: 2.2257x; 1.2444x over previous
//
#include <hip/hip_runtime.h>

#define NN 40000
#define DDIM 64
#define KE 16
#define EE 640000
#define BNEPS 1e-5f

// Finalize BN coefficients from raw sums: stats layout [sum[C], sumsq[C]].
__device__ __forceinline__ void bn_coeff(const float* __restrict__ S, int C, int c,
                                         const float* __restrict__ g, const float* __restrict__ b,
                                         float inv_n, float& sc, float& sh)
{
    float m   = S[c] * inv_n;
    float var = S[C + c] * inv_n - m * m;
    float r   = rsqrtf(var + BNEPS);
    sc = g[c] * r;
    sh = b[c] - m * sc;
}

// out[r][c] = sum_d f(in[r][d]) * W[d][c], 64x64 W, optional BN+ReLU input transform,
// optional raw column-stats accumulation on the output.
template<int TRN>
__global__ __launch_bounds__(256) void gemm64_k(
    const float* __restrict__ in,
    const float* __restrict__ W0, const float* __restrict__ W1, const float* __restrict__ W2,
    float* __restrict__ out0, float* __restrict__ out1, float* __restrict__ out2,
    const float* __restrict__ Sin, const float* __restrict__ gamma, const float* __restrict__ beta,
    float inv_n, float* __restrict__ Sout)
{
    const float* W = (blockIdx.y == 0) ? W0 : ((blockIdx.y == 1) ? W1 : W2);
    float* out     = (blockIdx.y == 0) ? out0 : ((blockIdx.y == 1) ? out1 : out2);

    __shared__ float Wl[64][64];
    __shared__ float inl[64][65];
    __shared__ float scl[64], shl[64];
    __shared__ float ssum[64], ssq[64];

    const int t = threadIdx.x;
    if (t < 64) {
        if (TRN) { float sc, sh; bn_coeff(Sin, 64, t, gamma, beta, inv_n, sc, sh); scl[t] = sc; shl[t] = sh; }
        ssum[t] = 0.f; ssq[t] = 0.f;
    }
#pragma unroll
    for (int i = 0; i < 16; i++) { int idx = t + i * 256; Wl[idx >> 6][idx & 63] = W[idx]; }
    __syncthreads();

    const int rbase = blockIdx.x * 64;
    {
        const int d = t & 63;
        float sc = 0.f, sh = 0.f;
        if (TRN) { sc = scl[d]; sh = shl[d]; }
#pragma unroll
        for (int i = 0; i < 16; i++) {
            int r = (t >> 6) + i * 4;
            float v = in[(size_t)(rbase + r) * 64 + d];
            if (TRN) v = fmaxf(fmaf(v, sc, sh), 0.f);
            inl[r][d] = v;
        }
    }
    __syncthreads();

    const int c0 = (t & 15) * 4, r0 = (t >> 4) * 4;
    float acc[4][4] = {};
#pragma unroll 16
    for (int d = 0; d < 64; d++) {
        float4 w4 = *(const float4*)&Wl[d][c0];
#pragma unroll
        for (int i = 0; i < 4; i++) {
            float h = inl[r0 + i][d];
            acc[i][0] = fmaf(h, w4.x, acc[i][0]);
            acc[i][1] = fmaf(h, w4.y, acc[i][1]);
            acc[i][2] = fmaf(h, w4.z, acc[i][2]);
            acc[i][3] = fmaf(h, w4.w, acc[i][3]);
        }
    }
#pragma unroll
    for (int i = 0; i < 4; i++) {
        float4 o; o.x = acc[i][0]; o.y = acc[i][1]; o.z = acc[i][2]; o.w = acc[i][3];
        *(float4*)&out[(size_t)(rbase + r0 + i) * 64 + c0] = o;
    }
    if (Sout) {
#pragma unroll
        for (int j = 0; j < 4; j++) {
            float s  = acc[0][j] + acc[1][j] + acc[2][j] + acc[3][j];
            float qv = acc[0][j] * acc[0][j] + acc[1][j] * acc[1][j] + acc[2][j] * acc[2][j] + acc[3][j] * acc[3][j];
            atomicAdd(&ssum[c0 + j], s);
            atomicAdd(&ssq[c0 + j], qv);
        }
        __syncthreads();
        if (t < 64) { atomicAdd(&Sout[t], ssum[t]); atomicAdd(&Sout[64 + t], ssq[t]); }
    }
}

// q = (pos[dst]-pos[src]) @ Wp1 + bp1, stored SoA; raw stats (3 cols) — 6 atomics/BLOCK.
__global__ __launch_bounds__(256) void edge_q_k(
    const float* __restrict__ pos, const int* __restrict__ src,
    const float* __restrict__ Wp1, const float* __restrict__ bp1,
    float* __restrict__ q0, float* __restrict__ q1, float* __restrict__ q2,
    float* __restrict__ Sq)
{
    float w00 = Wp1[0], w01 = Wp1[1], w02 = Wp1[2];
    float w10 = Wp1[3], w11 = Wp1[4], w12 = Wp1[5];
    float w20 = Wp1[6], w21 = Wp1[7], w22 = Wp1[8];
    float c0 = bp1[0], c1 = bp1[1], c2 = bp1[2];
    float s0 = 0, s1 = 0, s2 = 0, p0 = 0, p1 = 0, p2 = 0;
    for (int e = blockIdx.x * blockDim.x + threadIdx.x; e < EE; e += gridDim.x * blockDim.x) {
        int sj = src[e]; int di = e >> 4;
        float r0 = pos[di * 3 + 0] - pos[sj * 3 + 0];
        float r1 = pos[di * 3 + 1] - pos[sj * 3 + 1];
        float r2 = pos[di * 3 + 2] - pos[sj * 3 + 2];
        float v0 = c0 + r0 * w00 + r1 * w10 + r2 * w20;
        float v1 = c1 + r0 * w01 + r1 * w11 + r2 * w21;
        float v2 = c2 + r0 * w02 + r1 * w12 + r2 * w22;
        q0[e] = v0; q1[e] = v1; q2[e] = v2;
        s0 += v0; s1 += v1; s2 += v2;
        p0 += v0 * v0; p1 += v1 * v1; p2 += v2 * v2;
    }
#pragma unroll
    for (int o = 32; o > 0; o >>= 1) {
        s0 += __shfl_down(s0, o); s1 += __shfl_down(s1, o); s2 += __shfl_down(s2, o);
        p0 += __shfl_down(p0, o); p1 += __shfl_down(p1, o); p2 += __shfl_down(p2, o);
    }
    __shared__ float sred[4][6];
    const int w = threadIdx.x >> 6;
    if ((threadIdx.x & 63) == 0) {
        sred[w][0] = s0; sred[w][1] = s1; sred[w][2] = s2;
        sred[w][3] = p0; sred[w][4] = p1; sred[w][5] = p2;
    }
    __syncthreads();
    if (threadIdx.x < 6) {
        float v = sred[0][threadIdx.x] + sred[1][threadIdx.x] + sred[2][threadIdx.x] + sred[3][threadIdx.x];
        atomicAdd(&Sq[threadIdx.x], v);
    }
}

// Store-free raw column stats of a0 = a_dst[dst] - a_src[src] + delta  (64 cols over E rows).
// Node-per-wave: adst row loaded once/node; src+q broadcast via shfl; 16 gathers in flight.
__global__ __launch_bounds__(256) void edge_a0_k(
    const float* __restrict__ q0, const float* __restrict__ q1, const float* __restrict__ q2,
    const int* __restrict__ src,
    const float* __restrict__ adst, const float* __restrict__ asrc,
    const float* __restrict__ Wp2, const float* __restrict__ bp2,
    const float* __restrict__ Sq, const float* __restrict__ gp, const float* __restrict__ bp_,
    float* __restrict__ Sa0)
{
    const int lane = threadIdx.x & 63;
    const int wv   = blockIdx.x * (blockDim.x >> 6) + (threadIdx.x >> 6);
    const int nwv  = gridDim.x * (blockDim.x >> 6);
    const float inv_e = 1.0f / (float)EE;
    float sc30, sh30, sc31, sh31, sc32, sh32;
    bn_coeff(Sq, 3, 0, gp, bp_, inv_e, sc30, sh30);
    bn_coeff(Sq, 3, 1, gp, bp_, inv_e, sc31, sh31);
    bn_coeff(Sq, 3, 2, gp, bp_, inv_e, sc32, sh32);
    float w0 = Wp2[lane], w1 = Wp2[64 + lane], w2 = Wp2[128 + lane], bd = bp2[lane];
    float s = 0.f, sq = 0.f;
    for (int i = wv; i < NN; i += nwv) {
        const int e0 = i << 4;
        float ad  = adst[(size_t)i * 64 + lane];
        int   sv  = src[e0 + (lane & 15)];
        float qv0 = q0[e0 + (lane & 15)];
        float qv1 = q1[e0 + (lane & 15)];
        float qv2 = q2[e0 + (lane & 15)];
        int sidx[16];
#pragma unroll
        for (int k = 0; k < 16; k++) sidx[k] = __shfl(sv, k);
        float av[16];
#pragma unroll
        for (int k = 0; k < 16; k++) av[k] = asrc[(size_t)sidx[k] * 64 + lane];
#pragma unroll
        for (int k = 0; k < 16; k++) {
            float ph0 = fmaxf(fmaf(__shfl(qv0, k), sc30, sh30), 0.f);
            float ph1 = fmaxf(fmaf(__shfl(qv1, k), sc31, sh31), 0.f);
            float ph2 = fmaxf(fmaf(__shfl(qv2, k), sc32, sh32), 0.f);
            float dl  = bd + ph0 * w0 + ph1 * w1 + ph2 * w2;
            float a0v = ad - av[k] + dl;
            s += a0v; sq += a0v * a0v;
        }
    }
    __shared__ float ls[64], lq[64];
    if (threadIdx.x < 64) { ls[threadIdx.x] = 0.f; lq[threadIdx.x] = 0.f; }
    __syncthreads();
    atomicAdd(&ls[lane], s); atomicAdd(&lq[lane], sq);
    __syncthreads();
    if (threadIdx.x < 64) { atomicAdd(&Sa0[threadIdx.x], ls[threadIdx.x]); atomicAdd(&Sa0[64 + threadIdx.x], lq[threadIdx.x]); }
}

// t = relu(bn(a0)) @ Wa1 + ba1  [E,8]; node-per-wave staging (16 gathers in flight),
// 4 nodes (64 edges) per block per group; thread computes 2 outputs for one edge.
__global__ __launch_bounds__(256) void edge_t_k(
    const float* __restrict__ q0, const float* __restrict__ q1, const float* __restrict__ q2,
    const int* __restrict__ src,
    const float* __restrict__ adst, const float* __restrict__ asrc,
    const float* __restrict__ Wp2, const float* __restrict__ bp2,
    const float* __restrict__ Sq, const float* __restrict__ gp, const float* __restrict__ bp_,
    const float* __restrict__ Sa0, const float* __restrict__ ga0, const float* __restrict__ ba0,
    const float* __restrict__ Wa1, const float* __restrict__ ba1,
    float* __restrict__ tout, float* __restrict__ St)
{
    __shared__ float a1l[64][65];
    __shared__ float wl[64][8];
    __shared__ float red[16];
    const int t = threadIdx.x;
    const int lane = t & 63;
    const int w = t >> 6;                 // wave id 0..3 = node-in-group
    const float inv_e = 1.0f / (float)EE;
    float sc30, sh30, sc31, sh31, sc32, sh32;
    bn_coeff(Sq, 3, 0, gp, bp_, inv_e, sc30, sh30);
    bn_coeff(Sq, 3, 1, gp, bp_, inv_e, sc31, sh31);
    bn_coeff(Sq, 3, 2, gp, bp_, inv_e, sc32, sh32);
    float scA, shA; bn_coeff(Sa0, 64, lane, ga0, ba0, inv_e, scA, shA);
    float w0 = Wp2[lane], w1 = Wp2[64 + lane], w2 = Wp2[128 + lane], bd = bp2[lane];
    for (int i = t; i < 512; i += 256) wl[i >> 3][i & 7] = Wa1[i];
    if (t < 16) red[t] = 0.f;

    const int eL = t >> 2;                // local edge 0..63 (GEMM phase)
    const int j0 = (t & 3) * 2;           // output pair
    float bA = ba1[j0], bB = ba1[j0 + 1];
    float ssA = 0.f, spA = 0.f, ssB = 0.f, spB = 0.f;

    for (int g = blockIdx.x; g < NN / 4; g += gridDim.x) {
        __syncthreads();                  // protect a1l reuse
        {   // stage node i = g*4 + w (16 edges) into a1l[w*16 + k][lane]
            const int i  = g * 4 + w;
            const int e0 = i << 4;
            float ad  = adst[(size_t)i * 64 + lane];
            int   sv  = src[e0 + (lane & 15)];
            float qv0 = q0[e0 + (lane & 15)];
            float qv1 = q1[e0 + (lane & 15)];
            float qv2 = q2[e0 + (lane & 15)];
            int sidx[16];
#pragma unroll
            for (int k = 0; k < 16; k++) sidx[k] = __shfl(sv, k);
            float av[16];
#pragma unroll
            for (int k = 0; k < 16; k++) av[k] = asrc[(size_t)sidx[k] * 64 + lane];
#pragma unroll
            for (int k = 0; k < 16; k++) {
                float ph0 = fmaxf(fmaf(__shfl(qv0, k), sc30, sh30), 0.f);
                float ph1 = fmaxf(fmaf(__shfl(qv1, k), sc31, sh31), 0.f);
                float ph2 = fmaxf(fmaf(__shfl(qv2, k), sc32, sh32), 0.f);
                float dl  = bd + ph0 * w0 + ph1 * w1 + ph2 * w2;
                float a0v = ad - av[k] + dl;
                a1l[w * 16 + k][lane] = fmaxf(fmaf(a0v, scA, shA), 0.f);
            }
        }
        __syncthreads();
        {   // GEMM: t[e][j0], t[e][j0+1]
            float acc0 = bA, acc1 = bB;
#pragma unroll 16
            for (int dd = 0; dd < 64; dd++) {
                float a = a1l[eL][dd];
                acc0 = fmaf(a, wl[dd][j0], acc0);
                acc1 = fmaf(a, wl[dd][j0 + 1], acc1);
            }
            int e = g * 64 + eL;
            float2 o; o.x = acc0; o.y = acc1;
            *(float2*)&tout[(size_t)e * 8 + j0] = o;
            ssA += acc0; spA += acc0 * acc0;
            ssB += acc1; spB += acc1 * acc1;
        }
    }
    __syncthreads();
    atomicAdd(&red[j0], ssA);     atomicAdd(&red[j0 + 1], ssB);
    atomicAdd(&red[8 + j0], spA); atomicAdd(&red[8 + j0 + 1], spB);
    __syncthreads();
    if (t < 16) atomicAdd(&St[t], red[t]);
}

// Per-node (wave) fused: a2=relu(bn(t)); a3=a2@Wa2+ba2; softmax over 16 edges; agg; raw stats.
__global__ __launch_bounds__(256) void edge_final_k(
    const float* __restrict__ tin,
    const float* __restrict__ q0, const float* __restrict__ q1, const float* __restrict__ q2,
    const int* __restrict__ src, const float* __restrict__ vv,
    const float* __restrict__ Wp2, const float* __restrict__ bp2,
    const float* __restrict__ Sq, const float* __restrict__ gp, const float* __restrict__ bp_,
    const float* __restrict__ St, const float* __restrict__ ga1, const float* __restrict__ bb1,
    const float* __restrict__ Wa2, const float* __restrict__ ba2,
    float* __restrict__ agg, float* __restrict__ Sagg)
{
    const int t = threadIdx.x, lane = t & 63, w = t >> 6;
    const float inv_e = 1.0f / (float)EE;
    float sc3[3], sh3[3];
#pragma unroll
    for (int k = 0; k < 3; k++) bn_coeff(Sq, 3, k, gp, bp_, inv_e, sc3[k], sh3[k]);
    float sc8[8], sh8[8];
#pragma unroll
    for (int k = 0; k < 8; k++) bn_coeff(St, 8, k, ga1, bb1, inv_e, sc8[k], sh8[k]);
    float wa[8];
#pragma unroll
    for (int k = 0; k < 8; k++) wa[k] = Wa2[k * 64 + lane];
    float bad = ba2[lane];
    float wp0 = Wp2[lane], wp1 = Wp2[64 + lane], wp2 = Wp2[128 + lane];
    float bpd = bp2[lane];
    float ssum = 0.f, ssq = 0.f;

    for (int nn = 0; nn < 4; nn++) {
        int i = blockIdx.x * 16 + nn * 4 + w;
        float ax[16], dl[16], vs[16];
        float m = -3.0e38f;
#pragma unroll
        for (int j = 0; j < 16; j++) {
            int e = i * 16 + j;
            const float4* tp = (const float4*)(tin + (size_t)e * 8);
            float4 ta = tp[0], tb = tp[1];
            float a20 = fmaxf(fmaf(ta.x, sc8[0], sh8[0]), 0.f);
            float a21 = fmaxf(fmaf(ta.y, sc8[1], sh8[1]), 0.f);
            float a22 = fmaxf(fmaf(ta.z, sc8[2], sh8[2]), 0.f);
            float a23 = fmaxf(fmaf(ta.w, sc8[3], sh8[3]), 0.f);
            float a24 = fmaxf(fmaf(tb.x, sc8[4], sh8[4]), 0.f);
            float a25 = fmaxf(fmaf(tb.y, sc8[5], sh8[5]), 0.f);
            float a26 = fmaxf(fmaf(tb.z, sc8[6], sh8[6]), 0.f);
            float a27 = fmaxf(fmaf(tb.w, sc8[7], sh8[7]), 0.f);
            float a = bad;
            a = fmaf(a20, wa[0], a); a = fmaf(a21, wa[1], a);
            a = fmaf(a22, wa[2], a); a = fmaf(a23, wa[3], a);
            a = fmaf(a24, wa[4], a); a = fmaf(a25, wa[5], a);
            a = fmaf(a26, wa[6], a); a = fmaf(a27, wa[7], a);
            float ph0 = fmaxf(fmaf(q0[e], sc3[0], sh3[0]), 0.f);
            float ph1 = fmaxf(fmaf(q1[e], sc3[1], sh3[1]), 0.f);
            float ph2 = fmaxf(fmaf(q2[e], sc3[2], sh3[2]), 0.f);
            dl[j] = bpd + ph0 * wp0 + ph1 * wp1 + ph2 * wp2;
            vs[j] = vv[(size_t)src[e] * 64 + lane];
            ax[j] = a; m = fmaxf(m, a);
        }
        float s = 0.f;
#pragma unroll
        for (int j = 0; j < 16; j++) { ax[j] = __expf(ax[j] - m); s += ax[j]; }
        float inv = 1.0f / (s + 1e-16f);
        float ag = 0.f;
#pragma unroll
        for (int j = 0; j < 16; j++) ag += ax[j] * (vs[j] + dl[j]);
        ag *= inv;
        agg[(size_t)i * 64 + lane] = ag;
        ssum += ag; ssq += ag * ag;
    }
    __shared__ float ls[64], lq[64];
    if (t < 64) { ls[t] = 0.f; lq[t] = 0.f; }
    __syncthreads();
    atomicAdd(&ls[lane], ssum); atomicAdd(&lq[lane], ssq);
    __syncthreads();
    if (t < 64) { atomicAdd(&Sagg[t], ls[t]); atomicAdd(&Sagg[64 + t], lq[t]); }
}

// out = relu(bn(t2,g3,b3) + x)
__global__ __launch_bounds__(256) void final_k(
    const float* __restrict__ t2, const float* __restrict__ x,
    const float* __restrict__ St2, const float* __restrict__ g3, const float* __restrict__ b3,
    float* __restrict__ out)
{
    __shared__ float scl[64], shl[64];
    const int t = threadIdx.x;
    if (t < 64) { float sc, sh; bn_coeff(St2, 64, t, g3, b3, 1.0f / (float)NN, sc, sh); scl[t] = sc; shl[t] = sh; }
    __syncthreads();
    int idx = blockIdx.x * 256 + t;          // float4 index; NN*64/4 = 640000 exactly
    int c0 = (idx & 15) * 4;
    const float4 a = *(const float4*)&t2[(size_t)idx * 4];
    const float4 b = *(const float4*)&x[(size_t)idx * 4];
    float4 o;
    o.x = fmaxf(fmaf(a.x, scl[c0 + 0], shl[c0 + 0]) + b.x, 0.f);
    o.y = fmaxf(fmaf(a.y, scl[c0 + 1], shl[c0 + 1]) + b.y, 0.f);
    o.z = fmaxf(fmaf(a.z, scl[c0 + 2], shl[c0 + 2]) + b.z, 0.f);
    o.w = fmaxf(fmaf(a.w, scl[c0 + 3], shl[c0 + 3]) + b.w, 0.f);
    *(float4*)&out[(size_t)idx * 4] = o;
}

extern "C" void kernel_launch(void* const* d_in, const int* in_sizes, int n_in,
                              void* d_out, int out_size, void* d_ws, size_t ws_size,
                              hipStream_t stream)
{
    const float* x    = (const float*)d_in[0];
    const float* pos  = (const float*)d_in[1];
    const int*   src  = (const int*)d_in[2];      // edge_index[0]; dst[e] == e>>4 by construction
    const float* W_in = (const float*)d_in[3];
    const float* g1   = (const float*)d_in[4];
    const float* b1   = (const float*)d_in[5];
    const float* W_v  = (const float*)d_in[6];
    const float* W_src= (const float*)d_in[7];
    const float* W_dst= (const float*)d_in[8];
    const float* Wp1  = (const float*)d_in[9];
    const float* bp1  = (const float*)d_in[10];
    const float* gp   = (const float*)d_in[11];
    const float* bp_  = (const float*)d_in[12];
    const float* Wp2  = (const float*)d_in[13];
    const float* bp2  = (const float*)d_in[14];
    const float* ga0  = (const float*)d_in[15];
    const float* ba0  = (const float*)d_in[16];
    const float* Wa1  = (const float*)d_in[17];
    const float* ba1  = (const float*)d_in[18];
    const float* ga1  = (const float*)d_in[19];
    const float* bb1  = (const float*)d_in[20];
    const float* Wa2  = (const float*)d_in[21];
    const float* ba2  = (const float*)d_in[22];
    const float* g2   = (const float*)d_in[23];
    const float* b2   = (const float*)d_in[24];
    const float* W_out= (const float*)d_in[25];
    const float* g3   = (const float*)d_in[26];
    const float* b3   = (const float*)d_in[27];
    float* out = (float*)d_out;

    float* wsf   = (float*)d_ws;
    float* S_t1  = wsf;          // 128
    float* S_q   = wsf + 128;    // 6 used
    float* S_a0  = wsf + 192;    // 128
    float* S_t   = wsf + 320;    // 16 used
    float* S_agg = wsf + 384;    // 128
    float* S_t2  = wsf + 512;    // 128
    const size_t N64 = (size_t)NN * 64;
    float* t1   = wsf + 1024;
    float* asrc = t1 + N64;
    float* adst = asrc + N64;
    float* vv   = adst + N64;
    float* q0   = vv + N64;
    float* q1   = q0 + EE;
    float* q2   = q1 + EE;
    float* tt   = q2 + EE;       // [E,8]
    float* agg  = t1;            // alias: t1 dead after gemm #2
    float* t2   = asrc;          // alias: asrc dead after edge_t

    hipMemsetAsync(wsf, 0, 1024 * sizeof(float), stream);

    // t1 = x @ W_in (+stats)
    gemm64_k<0><<<dim3(625, 1), 256, 0, stream>>>(x, W_in, W_in, W_in, t1, t1, t1,
                                                  nullptr, nullptr, nullptr, 0.f, S_t1);
    // h = relu(bn(t1)); {asrc,adst,vv} = h @ {W_src,W_dst,W_v}
    gemm64_k<1><<<dim3(625, 3), 256, 0, stream>>>(t1, W_src, W_dst, W_v, asrc, adst, vv,
                                                  S_t1, g1, b1, 1.0f / (float)NN, nullptr);
    // q = (pos[dst]-pos[src]) @ Wp1 + bp1 (+stats3) — 6 atomics/block
    edge_q_k<<<256, 256, 0, stream>>>(pos, src, Wp1, bp1, q0, q1, q2, S_q);
    // raw stats of a0 (store-free) — node-per-wave, 2048 blocks for latency hiding
    edge_a0_k<<<2048, 256, 0, stream>>>(q0, q1, q2, src, adst, asrc, Wp2, bp2, S_q, gp, bp_, S_a0);
    // t = relu(bn(a0)) @ Wa1 + ba1 (+stats8) — node-per-wave staging, 2048 blocks
    edge_t_k<<<2048, 256, 0, stream>>>(q0, q1, q2, src, adst, asrc, Wp2, bp2, S_q, gp, bp_,
                                       S_a0, ga0, ba0, Wa1, ba1, tt, S_t);
    // a2,a3,softmax,agg (+stats)
    edge_final_k<<<2500, 256, 0, stream>>>(tt, q0, q1, q2, src, vv, Wp2, bp2, S_q, gp, bp_,
                                           S_t, ga1, bb1, Wa2, ba2, agg, S_agg);
    // t2 = relu(bn(agg,g2,b2)) @ W_out (+stats)
    gemm64_k<1><<<dim3(625, 1), 256, 0, stream>>>(agg, W_out, W_out, W_out, t2, t2, t2,
                                                  S_agg, g2, b2, 1.0f / (float)NN, S_t2);
    // out = relu(bn(t2,g3,b3) + x)
    final_k<<<2500, 256, 0, stream>>>(t2, x, S_t2, g3, b3, out);
}